// Round 12
// baseline (1289.127 us; speedup 1.0000x reference)
//
#include <hip/hip_runtime.h>
#include <hip/hip_fp16.h>

#define N_NODES   100000
#define N_EDGES   1600000
#define IN_CH     128
#define HID       64
#define N_CLASSES 16
#define N_GRAPHS  64

#define BK_SH     9                          // bucket = dst >> 9 (512 nodes/bucket)
#define BK_NODES  512
#define NB        ((N_NODES + BK_NODES - 1) / BK_NODES)   // 196 buckets
#define BK_CAP    10240                      // fixed bucket capacity (mean 8163, +23 sigma)
#define CH_EDGES  4096
#define EPT       16                         // edges/thread in binscatter (256 thr)
#define NCH       ((N_EDGES + CH_EDGES - 1) / CH_EDGES)   // 391 chunks
#define AGG_NPW   2    // nodes per wave; 12500 blocks x 8 nodes = exact cover
#define AGG_BLOCKS (N_NODES / (4 * AGG_NPW))              // 12500

typedef __attribute__((ext_vector_type(8))) short bf16x8;
typedef __attribute__((ext_vector_type(4))) float f32x4;
typedef __attribute__((ext_vector_type(4))) unsigned u32x4;
typedef __attribute__((ext_vector_type(2))) unsigned u32x2;

__device__ __forceinline__ unsigned short f2bf(float f) {   // RNE f32->bf16
    unsigned u = __float_as_uint(f);
    u += 0x7fffu + ((u >> 16) & 1u);
    return (unsigned short)(u >> 16);
}
__device__ __forceinline__ f32x4 bf4v(uint2 v) {            // 4 bf16 -> f32x4
    u32x4 u;
    u.x = v.x << 16; u.y = v.x & 0xffff0000u;
    u.z = v.y << 16; u.w = v.y & 0xffff0000u;
    return __builtin_bit_cast(f32x4, u);
}
// csr entry: src (17 bits) | fp16(ew) sign-free (15 bits) << 17
__device__ __forceinline__ float dec_ew(unsigned v) {
    return __half2float(__ushort_as_half((unsigned short)(v >> 17)));
}

// ---- SRSRC buffer view: 32-bit voffset addressing for random gathers ----
#if __has_builtin(__builtin_amdgcn_make_buffer_rsrc) && \
    __has_builtin(__builtin_amdgcn_raw_buffer_load_b32) && \
    __has_builtin(__builtin_amdgcn_raw_buffer_load_b64)
struct BufView {
    __amdgpu_buffer_rsrc_t rsrc;
    __device__ __forceinline__ void init(const void* p) {
        rsrc = __builtin_amdgcn_make_buffer_rsrc((void*)p, (short)0,
                                                 (int)0xFFFFFFFF, 0x00020000);
    }
    __device__ __forceinline__ unsigned ld32(unsigned off) const {
        return __builtin_amdgcn_raw_buffer_load_b32(rsrc, (int)off, 0, 0);
    }
    __device__ __forceinline__ uint2 ld64(unsigned off) const {
        u32x2 r = __builtin_amdgcn_raw_buffer_load_b64(rsrc, (int)off, 0, 0);
        return make_uint2(r.x, r.y);
    }
};
#else
struct BufView {
    const char* base;
    __device__ __forceinline__ void init(const void* p) { base = (const char*)p; }
    __device__ __forceinline__ unsigned ld32(unsigned off) const {
        return *(const unsigned*)(base + off);
    }
    __device__ __forceinline__ uint2 ld64(unsigned off) const {
        return *(const uint2*)(base + off);
    }
};
#endif

// ---------------------------------------------------------------- bin scatter (staged)
// bcursor is zero-initialized (memset); absolute base = t*BK_CAP + running count.
__global__ void k_binscatter(const int* __restrict__ src, const int* __restrict__ dst,
                             const float* __restrict__ ew, int* __restrict__ bcursor,
                             int2* __restrict__ bedges) {
    __shared__ int  hist[NB];
    __shared__ int  offs[NB];
    __shared__ int  gbase[NB];
    __shared__ int  sc[256];
    __shared__ int2 stage[CH_EDGES];
    __shared__ int  dest[CH_EDGES];
    const int t = threadIdx.x;
    const int base = blockIdx.x * CH_EDGES;
    const int nloc = min(CH_EDGES, N_EDGES - base);

    for (int i = t; i < NB; i += 256) hist[i] = 0;
    __syncthreads();

    int myb[EPT], myr[EPT], myp[EPT]; float myw[EPT];
#pragma unroll
    for (int j = 0; j < EPT; ++j) {
        int i = base + j * 256 + t;
        if (i < N_EDGES) {
            int s = src[i], d = dst[i];
            int b = d >> BK_SH;
            myb[j] = b;
            myr[j] = atomicAdd(&hist[b], 1);
            myp[j] = s | ((d & (BK_NODES - 1)) << 17);
            myw[j] = ew[i];
        } else {
            myb[j] = -1;
        }
    }
    __syncthreads();

    int v = (t < NB) ? hist[t] : 0;
    sc[t] = v;
    __syncthreads();
    for (int off = 1; off < 256; off <<= 1) {
        int a = (t >= off) ? sc[t - off] : 0;
        __syncthreads();
        sc[t] += a;
        __syncthreads();
    }
    if (t < NB) {
        offs[t] = sc[t] - v;
        gbase[t] = t * BK_CAP + ((v > 0) ? atomicAdd(&bcursor[t], v) : 0);
    }
    __syncthreads();

#pragma unroll
    for (int j = 0; j < EPT; ++j) {
        if (myb[j] >= 0) {
            int p = offs[myb[j]] + myr[j];
            stage[p] = make_int2(myp[j], __float_as_int(myw[j]));
            dest[p] = gbase[myb[j]] + myr[j];
        }
    }
    __syncthreads();

    for (int i = t; i < nloc; i += 256)
        bedges[dest[i]] = stage[i];
}

// ---------------------------------------------------------------- build (fused)
// Grid NB+1: block NB performs the one-time bf16 weight transposes (w1t/w2t)
// consumed by gemm1 / fused agg1 epilogue; blocks 0..NB-1 build buckets.
__global__ __launch_bounds__(256) void k_build(const int* __restrict__ bcursor,
                                               const int2* __restrict__ bedges,
                                               int2* __restrict__ rowse,
                                               float* __restrict__ dis,
                                               unsigned* __restrict__ csr,
                                               const float* __restrict__ W1,
                                               const float* __restrict__ W2,
                                               unsigned short* __restrict__ w1t,
                                               unsigned short* __restrict__ w2t) {
    const int b = blockIdx.x;
    const int t = threadIdx.x;

    if (b == NB) {   // weight-transpose block
        for (int i = t; i < IN_CH * HID; i += 256) {   // w1t[n*128+k] = bf16(W1[k][n])
            int n = i >> 7, k = i & 127;
            w1t[i] = f2bf(W1[k * HID + n]);
        }
        for (int i = t; i < HID * HID; i += 256) {     // w2t[n*64+k] = bf16(W2[k][n])
            int n = i >> 6, k = i & 63;
            w2t[i] = f2bf(W2[k * HID + n]);
        }
        return;
    }

    __shared__ int2  eds[BK_CAP];         // 80 KB
    __shared__ int   cnt[BK_NODES];
    __shared__ float dsum[BK_NODES];
    __shared__ int   cur[BK_NODES];
    __shared__ int   sc[256];
    const int beg = b * BK_CAP;
    const int n = bcursor[b];             // per-bucket edge count

    for (int i = t; i < BK_NODES; i += 256) { cnt[i] = 0; dsum[i] = 0.0f; }
    __syncthreads();

    for (int i = t; i < n; i += 256) {
        int2 e = bedges[beg + i];
        eds[i] = e;
        int dl = ((unsigned)e.x) >> 17;
        atomicAdd(&cnt[dl], 1);
        atomicAdd(&dsum[dl], __int_as_float(e.y));
    }
    __syncthreads();

    int a0 = cnt[2 * t], a1 = cnt[2 * t + 1];
    int pair = a0 + a1;
    sc[t] = pair;
    __syncthreads();
    for (int off = 1; off < 256; off <<= 1) {
        int a = (t >= off) ? sc[t - off] : 0;
        __syncthreads();
        sc[t] += a;
        __syncthreads();
    }
    int excl = sc[t] - pair;
    cur[2 * t] = excl;
    cur[2 * t + 1] = excl + a0;
    {
        int n0 = b * BK_NODES + 2 * t;
        if (n0 < N_NODES) {
            rowse[n0] = make_int2(beg + excl, beg + excl + a0);
            dis[n0] = rsqrtf(1.0f + dsum[2 * t]);
        }
        int n1 = n0 + 1;
        if (n1 < N_NODES) {
            rowse[n1] = make_int2(beg + excl + a0, beg + excl + a0 + a1);
            dis[n1] = rsqrtf(1.0f + dsum[2 * t + 1]);
        }
    }
    __syncthreads();

    for (int i = t; i < n; i += 256) {
        int2 e = eds[i];
        int dl = ((unsigned)e.x) >> 17;
        int s = e.x & 0x1FFFF;
        unsigned short w16 = __half_as_ushort(__float2half(__int_as_float(e.y)));
        int pos = beg + atomicAdd(&cur[dl], 1);
        csr[pos] = (unsigned)s | ((unsigned)w16 << 17);
    }
}

// ---------------------------------------------------------------- GEMM via MFMA (layer 1)
// Epilogue scales by dis[row]: hb = bf16(dis * (x@W))  [norm factoring]
// Weights come pre-transposed+pre-converted (w1t): staging is a straight copy.
template <int K>
__global__ __launch_bounds__(256) void k_gemm(const float* __restrict__ x,
                                              const unsigned short* __restrict__ w1t,
                                              const float* __restrict__ dis,
                                              unsigned short* __restrict__ hb) {
    constexpr int AS = K + 8;            // padded stride in bf16 elems
    __shared__ unsigned short wt[64 * AS];    // wt[n][k] = W[k][n]
    __shared__ unsigned short a_s[64 * AS];   // a_s[row][k]
    const int t    = threadIdx.x;
    const int lane = t & 63;
    const int wave = t >> 6;
    const int m    = lane & 15;
    const int quad = lane >> 4;
    const int rowbase = blockIdx.x * 64;

    constexpr int CPR = K / 8;
    for (int c = t; c < 64 * CPR; c += 256) {
        int row = c / CPR, cc = c % CPR;
        int gr = rowbase + row;
        float4 v0, v1;
        if (gr < N_NODES) {
            v0 = *(const float4*)&x[(long)gr * K + cc * 8];
            v1 = *(const float4*)&x[(long)gr * K + cc * 8 + 4];
        } else {
            v0 = make_float4(0.f, 0.f, 0.f, 0.f); v1 = v0;
        }
        uint4 p;
        p.x = f2bf(v0.x) | ((unsigned)f2bf(v0.y) << 16);
        p.y = f2bf(v0.z) | ((unsigned)f2bf(v0.w) << 16);
        p.z = f2bf(v1.x) | ((unsigned)f2bf(v1.y) << 16);
        p.w = f2bf(v1.z) | ((unsigned)f2bf(v1.w) << 16);
        *(uint4*)&a_s[row * AS + cc * 8] = p;
    }
    // straight uint4 copy: coalesced global read, contiguous LDS write
    for (int idx = t; idx < 64 * CPR; idx += 256) {
        int n = idx / CPR, c = idx % CPR;
        *(uint4*)&wt[n * AS + c * 8] = *(const uint4*)&w1t[n * K + c * 8];
    }
    __syncthreads();

    bf16x8 afrag[K / 32];
#pragma unroll
    for (int ks = 0; ks < K / 32; ++ks)
        afrag[ks] = *(const bf16x8*)&a_s[(wave * 16 + m) * AS + ks * 32 + quad * 8];

    bf16x8 bfrag[4][K / 32];
#pragma unroll
    for (int nt = 0; nt < 4; ++nt)
#pragma unroll
        for (int ks = 0; ks < K / 32; ++ks)
            bfrag[nt][ks] = *(const bf16x8*)&wt[(nt * 16 + m) * AS + ks * 32 + quad * 8];

    f32x4 acc[4];
#pragma unroll
    for (int nt = 0; nt < 4; ++nt) acc[nt] = (f32x4){0.f, 0.f, 0.f, 0.f};

#pragma unroll
    for (int ks = 0; ks < K / 32; ++ks) {
#pragma unroll
        for (int nt = 0; nt < 4; ++nt)
            acc[nt] = __builtin_amdgcn_mfma_f32_16x16x32_bf16(afrag[ks], bfrag[nt][ks],
                                                              acc[nt], 0, 0, 0);
    }

#pragma unroll
    for (int i = 0; i < 4; ++i) {
        int gr = rowbase + wave * 16 + quad * 4 + i;
        if (gr < N_NODES) {
            float dsc = dis[gr];
#pragma unroll
            for (int nt = 0; nt < 4; ++nt)
                hb[(long)gr * HID + nt * 16 + m] = f2bf(dsc * acc[nt][i]);
        }
    }
}

// ---------------------------------------------------------------- aggregate (gather)
// Round-6 proven dual-chain gather. Each wave owns 2 consecutive nodes as two
// concurrent csr->gather->FMA streams (2x MLP), merged full-block loop +
// per-chain leftovers + interleaved clamped tails.
// OB=true : FUSED layer-2 GEMM epilogue (bit-identical to former k_gemm<64>).
// OB=false: fused mean-pool + TAIL-BLOCK head (threadfence + done-counter; the
//           last block re-reads pooled via atomicAdd(p,0) and writes out).

// process one full block for chain X: consume loaded csr regs, advance, prefetch
#define FULLBLK(pX, eX, f_, x0, x1, x2, x3, accX)                             \
    do {                                                                      \
        const unsigned e0_ = x0, e1_ = x1, e2_ = x2, e3_ = x3;                \
        pX += 16;                                                             \
        f_ = (pX + 16 <= eX);                                                 \
        if (f_) {                                                             \
            const unsigned v_ = (unsigned)((pX + g) << 2);                    \
            x0 = vc.ld32(v_);      x1 = vc.ld32(v_ + 16);                     \
            x2 = vc.ld32(v_ + 32); x3 = vc.ld32(v_ + 48);                     \
        }                                                                     \
        f32x4 v0_ = bf4v(vh.ld64(((e0_ & 0x1FFFF) << 7) | coff));             \
        f32x4 v1_ = bf4v(vh.ld64(((e1_ & 0x1FFFF) << 7) | coff));             \
        f32x4 v2_ = bf4v(vh.ld64(((e2_ & 0x1FFFF) << 7) | coff));             \
        f32x4 v3_ = bf4v(vh.ld64(((e3_ & 0x1FFFF) << 7) | coff));             \
        accX += v0_ * dec_ew(e0_);                                            \
        accX += v1_ * dec_ew(e1_);                                            \
        accX += v2_ * dec_ew(e2_);                                            \
        accX += v3_ * dec_ew(e3_);                                            \
    } while (0)

template <bool OB>
__global__ void k_aggregate(const int2* __restrict__ rowse,
                            const unsigned* __restrict__ csr,
                            const uint2* __restrict__ hb, const float* __restrict__ dis,
                            const float* __restrict__ b, const int* __restrict__ batch,
                            float* __restrict__ pooled,
                            unsigned short* __restrict__ hb2,
                            const unsigned short* __restrict__ w2t,
                            int* __restrict__ done,
                            const float* __restrict__ Wl, const float* __restrict__ bl,
                            float* __restrict__ out) {
    __shared__ float psh[4 * AGG_NPW][HID];        // 2 KB (pool path)
    __shared__ unsigned short wt2[64 * (HID + 8)]; // 9 KB W2 fragments (fuse path)
    __shared__ unsigned short prow[8][HID];        // 1 KB bf16 o-rows (fuse path)
    constexpr int AS2 = HID + 8;
    const int tid  = threadIdx.x;
    const int lane = tid & 63;
    const int g    = lane >> 4;          // edge group 0..3
    const int c4   = lane & 15;          // channel quad index
    const int wave = tid >> 6;
    const int node0 = (blockIdx.x * 4 + wave) * AGG_NPW;   // exact cover
    const int node1 = node0 + 1;
    const float4 bb = ((const float4*)b)[c4];
    const f32x4 bbv = {bb.x, bb.y, bb.z, bb.w};

    if constexpr (OB) {   // straight uint4 copy: coalesced read, contiguous write
        for (int idx = tid; idx < 64 * 8; idx += 256) {
            int n = idx >> 3, c = idx & 7;
            *(uint4*)&wt2[n * AS2 + c * 8] = *(const uint4*)&w2t[n * HID + c * 8];
        }
        __syncthreads();
    }

    BufView vc; vc.init(csr);            // 32-bit voffset addressing
    BufView vh; vh.init(hb);
    const unsigned coff = (unsigned)(c4 << 3);   // byte offset of my 8B slice in 128B row

    // both nodes' bounds (one 16B load, node0 even) + self-rows up front
    const int4 rr = *(const int4*)&rowse[node0];
    const uint2 hs0 = hb[node0 * 16 + c4];
    const uint2 hs1 = hb[node1 * 16 + c4];

    f32x4 acc0 = (g == 0) ? bf4v(hs0) : (f32x4){0.f, 0.f, 0.f, 0.f};
    f32x4 acc1 = (g == 0) ? bf4v(hs1) : (f32x4){0.f, 0.f, 0.f, 0.f};

    int p0 = rr.x; const int e0 = rr.y;
    int p1 = rr.z; const int e1 = rr.w;

    unsigned a0 = 0, a1 = 0, a2 = 0, a3 = 0;
    unsigned b0 = 0, b1 = 0, b2 = 0, b3 = 0;
    bool fA = (p0 + 16 <= e0);
    bool fB = (p1 + 16 <= e1);
    if (fA) {
        const unsigned v = (unsigned)((p0 + g) << 2);
        a0 = vc.ld32(v);      a1 = vc.ld32(v + 16);
        a2 = vc.ld32(v + 32); a3 = vc.ld32(v + 48);
    }
    if (fB) {
        const unsigned v = (unsigned)((p1 + g) << 2);
        b0 = vc.ld32(v);      b1 = vc.ld32(v + 16);
        b2 = vc.ld32(v + 32); b3 = vc.ld32(v + 48);
    }

    while (fA && fB) {          // both chains active: fully interleaved body
        FULLBLK(p0, e0, fA, a0, a1, a2, a3, acc0);
        FULLBLK(p1, e1, fB, b0, b1, b2, b3, acc1);
    }
    while (fA) FULLBLK(p0, e0, fA, a0, a1, a2, a3, acc0);
    while (fB) FULLBLK(p1, e1, fB, b0, b1, b2, b3, acc1);

    // interleaved clamped tails: issue both csr tail loads before any gather
    const bool tA = (p0 < e0);
    const bool tB = (p1 < e1);
    unsigned ta0 = 0, ta1 = 0, ta2 = 0, ta3 = 0;
    unsigned tb0 = 0, tb1 = 0, tb2 = 0, tb3 = 0;
    if (tA) {
        const int last = e0 - 1;
        ta0 = vc.ld32((unsigned)(min(p0 + g,      last) << 2));
        ta1 = vc.ld32((unsigned)(min(p0 + 4 + g,  last) << 2));
        ta2 = vc.ld32((unsigned)(min(p0 + 8 + g,  last) << 2));
        ta3 = vc.ld32((unsigned)(min(p0 + 12 + g, last) << 2));
    }
    if (tB) {
        const int last = e1 - 1;
        tb0 = vc.ld32((unsigned)(min(p1 + g,      last) << 2));
        tb1 = vc.ld32((unsigned)(min(p1 + 4 + g,  last) << 2));
        tb2 = vc.ld32((unsigned)(min(p1 + 8 + g,  last) << 2));
        tb3 = vc.ld32((unsigned)(min(p1 + 12 + g, last) << 2));
    }
    if (tA) {
        f32x4 v0 = bf4v(vh.ld64(((ta0 & 0x1FFFF) << 7) | coff));
        f32x4 v1 = bf4v(vh.ld64(((ta1 & 0x1FFFF) << 7) | coff));
        f32x4 v2 = bf4v(vh.ld64(((ta2 & 0x1FFFF) << 7) | coff));
        f32x4 v3 = bf4v(vh.ld64(((ta3 & 0x1FFFF) << 7) | coff));
        acc0 += v0 * ((p0 + g      < e0) ? dec_ew(ta0) : 0.f);
        acc0 += v1 * ((p0 + 4 + g  < e0) ? dec_ew(ta1) : 0.f);
        acc0 += v2 * ((p0 + 8 + g  < e0) ? dec_ew(ta2) : 0.f);
        acc0 += v3 * ((p0 + 12 + g < e0) ? dec_ew(ta3) : 0.f);
    }
    if (tB) {
        f32x4 v0 = bf4v(vh.ld64(((tb0 & 0x1FFFF) << 7) | coff));
        f32x4 v1 = bf4v(vh.ld64(((tb1 & 0x1FFFF) << 7) | coff));
        f32x4 v2 = bf4v(vh.ld64(((tb2 & 0x1FFFF) << 7) | coff));
        f32x4 v3 = bf4v(vh.ld64(((tb3 & 0x1FFFF) << 7) | coff));
        acc1 += v0 * ((p1 + g      < e1) ? dec_ew(tb0) : 0.f);
        acc1 += v1 * ((p1 + 4 + g  < e1) ? dec_ew(tb1) : 0.f);
        acc1 += v2 * ((p1 + 8 + g  < e1) ? dec_ew(tb2) : 0.f);
        acc1 += v3 * ((p1 + 12 + g < e1) ? dec_ew(tb3) : 0.f);
    }

    // cross-group reduce (4 groups of 16 lanes hold partial sums)
#pragma unroll
    for (int i = 0; i < 4; ++i) {
        float t0 = acc0[i];
        t0 += __shfl_xor(t0, 16); t0 += __shfl_xor(t0, 32);
        acc0[i] = t0;
        float t1 = acc1[i];
        t1 += __shfl_xor(t1, 16); t1 += __shfl_xor(t1, 32);
        acc1[i] = t1;
    }

    const float dd0 = dis[node0];
    const float dd1 = dis[node1];

    if (g == 0) {
        f32x4 o0 = acc0 * dd0 + bbv;
        f32x4 o1 = acc1 * dd1 + bbv;
        o0.x = fmaxf(o0.x, 0.f); o0.y = fmaxf(o0.y, 0.f);
        o0.z = fmaxf(o0.z, 0.f); o0.w = fmaxf(o0.w, 0.f);
        o1.x = fmaxf(o1.x, 0.f); o1.y = fmaxf(o1.y, 0.f);
        o1.z = fmaxf(o1.z, 0.f); o1.w = fmaxf(o1.w, 0.f);
        uint2 pk0, pk1;
        pk0.x = (unsigned)f2bf(o0.x) | ((unsigned)f2bf(o0.y) << 16);
        pk0.y = (unsigned)f2bf(o0.z) | ((unsigned)f2bf(o0.w) << 16);
        pk1.x = (unsigned)f2bf(o1.x) | ((unsigned)f2bf(o1.y) << 16);
        pk1.y = (unsigned)f2bf(o1.z) | ((unsigned)f2bf(o1.w) << 16);
        if constexpr (OB) {
            ((uint2*)prow)[(wave * 2) * 16 + c4]     = pk0;
            ((uint2*)prow)[(wave * 2 + 1) * 16 + c4] = pk1;
        } else {
            *(f32x4*)&psh[wave * AGG_NPW][c4 * 4] = o0;
            *(f32x4*)&psh[wave * AGG_NPW + 1][c4 * 4] = o1;
        }
    }

    if constexpr (OB) {    // ---- fused layer-2 mini-GEMM: hb2 = bf16(dis*(o@W2))
        __syncthreads();   // prow + wt2 visible to all
        const int mm = lane & 15;
        const int qq = lane >> 4;
        const int arow = wave * 2 + (mm < 2 ? mm : 0);   // rows>=2 are don't-care
        bf16x8 af0 = *(const bf16x8*)&prow[arow][qq * 8];
        bf16x8 af1 = *(const bf16x8*)&prow[arow][32 + qq * 8];
        f32x4 a2[4];
#pragma unroll
        for (int nt = 0; nt < 4; ++nt) a2[nt] = (f32x4){0.f, 0.f, 0.f, 0.f};
#pragma unroll
        for (int nt = 0; nt < 4; ++nt) {
            bf16x8 bf0 = *(const bf16x8*)&wt2[(nt * 16 + mm) * AS2 + qq * 8];
            a2[nt] = __builtin_amdgcn_mfma_f32_16x16x32_bf16(af0, bf0, a2[nt], 0, 0, 0);
        }
#pragma unroll
        for (int nt = 0; nt < 4; ++nt) {
            bf16x8 bf1 = *(const bf16x8*)&wt2[(nt * 16 + mm) * AS2 + 32 + qq * 8];
            a2[nt] = __builtin_amdgcn_mfma_f32_16x16x32_bf16(af1, bf1, a2[nt], 0, 0, 0);
        }
        if (qq == 0) {     // D: col=lane&15, row=(lane>>4)*4+i -> rows 0,1 here
#pragma unroll
            for (int nt = 0; nt < 4; ++nt) {
                hb2[(size_t)node0 * HID + nt * 16 + mm] = f2bf(dd0 * a2[nt][0]);
                hb2[(size_t)node1 * HID + nt * 16 + mm] = f2bf(dd1 * a2[nt][1]);
            }
        }
    }

    if constexpr (!OB) {   // fused mean-pool + tail-block head
        __syncthreads();
        if (tid < HID) {
            const int nb0 = blockIdx.x * 4 * AGG_NPW;
            int curg = batch[nb0];
            float a = 0.f;
#pragma unroll
            for (int j = 0; j < 4 * AGG_NPW; ++j) {
                int bg = batch[nb0 + j];
                if (bg != curg) {
                    atomicAdd(&pooled[curg * HID + tid], a);
                    a = 0.f; curg = bg;
                }
                a += psh[j][tid];
            }
            atomicAdd(&pooled[curg * HID + tid], a);
        }
        __syncthreads();
        __threadfence();                 // our pooled atomics visible device-wide
        __shared__ int lastFlag;
        if (tid == 0) lastFlag = (atomicAdd(done, 1) == AGG_BLOCKS - 1);
        __syncthreads();
        if (lastFlag) {                  // ---- head (former k_out), 256 threads
            __shared__ int bnd[N_GRAPHS + 1];
            __shared__ float pl[N_GRAPHS * HID];   // 16 KB
            if (tid <= N_GRAPHS) {       // first idx with batch[idx] >= tid
                int lo = 0, hi = N_NODES;
                while (lo < hi) {
                    int mid = (lo + hi) >> 1;
                    if (batch[mid] < tid) lo = mid + 1; else hi = mid;
                }
                bnd[tid] = lo;
            }
            for (int i = tid; i < N_GRAPHS * HID; i += 256)
                pl[i] = atomicAdd(&pooled[i], 0.0f);   // coherent read
            __syncthreads();
            for (int o = tid; o < N_GRAPHS * N_CLASSES; o += 256) {
                int gg = o >> 4, kk = o & 15;
                float cntg = (float)(bnd[gg + 1] - bnd[gg]);
                float inv = 1.0f / fmaxf(cntg, 1.0f);
                float acc = 0.f;
#pragma unroll
                for (int h = 0; h < HID; ++h)
                    acc += pl[gg * HID + h] * Wl[h * N_CLASSES + kk];
                out[o] = acc * inv + bl[kk];
            }
        }
    }
}

extern "C" void kernel_launch(void* const* d_in, const int* in_sizes, int n_in,
                              void* d_out, int out_size, void* d_ws, size_t ws_size,
                              hipStream_t stream) {
    const float* x     = (const float*)d_in[0];
    const int*   ei    = (const int*)d_in[1];
    const float* ew    = (const float*)d_in[2];
    const int*   batch = (const int*)d_in[3];
    const float* W1    = (const float*)d_in[4];
    const float* b1    = (const float*)d_in[5];
    const float* W2    = (const float*)d_in[6];
    const float* b2    = (const float*)d_in[7];
    const float* Wl    = (const float*)d_in[8];
    const float* bl    = (const float*)d_in[9];

    const int* srcv = ei;            // edge_index[0]
    const int* dstv = ei + N_EDGES;  // edge_index[1]

    // workspace layout (all offsets 16B-aligned); zero-init region first
    char* wsb = (char*)d_ws;
    int*            bcursor= (int*)wsb;                wsb += 1024;             // counts (zeroed)
    float*          pooled = (float*)wsb;              wsb += N_GRAPHS * HID * 4; // 16 KB (zeroed)
    int*            done   = (int*)wsb;                wsb += 64;               // counter (zeroed)
    float*          dis    = (float*)wsb;              wsb += 100352 * 4;
    int2*           rowse  = (int2*)wsb;               wsb += 100352 * 8;   // {beg,end}/node
    unsigned*       csr    = (unsigned*)wsb;           wsb += (size_t)NB * BK_CAP * 4;
    unsigned short* hb     = (unsigned short*)wsb;     wsb += N_NODES * HID * 2;  // bf16 dis*h (layer1)
    char*           scratch= wsb;                      wsb += N_NODES * HID * 4;
    unsigned short* w1t    = (unsigned short*)wsb;     wsb += IN_CH * HID * 2;  // bf16 W1^T
    unsigned short* w2t    = (unsigned short*)wsb;     wsb += HID * HID * 2;    // bf16 W2^T
    float*          out    = (float*)d_out;
    int2*           bedges = (int2*)scratch;           // dead after k_build
    unsigned short* hb2    = (unsigned short*)scratch; // layer-2 gather rows (bf16),
                                                       // written by fused agg1 epilogue

    // ---- zero bcursor + pooled + done in one memset (replaces k_init)
    hipMemsetAsync(bcursor, 0, 1024 + N_GRAPHS * HID * 4 + 64, stream);

    // ---- CSR build (counting sort, fixed-capacity buckets, fused build + W transpose)
    k_binscatter<<<NCH, 256, 0, stream>>>(srcv, dstv, ew, bcursor, bedges);
    k_build<<<NB + 1, 256, 0, stream>>>(bcursor, bedges, rowse, dis, csr,
                                        W1, W2, w1t, w2t);

    // ---- layer 1 GEMM
    k_gemm<IN_CH><<<(N_NODES + 63) / 64, 256, 0, stream>>>(x, w1t, dis, hb);
    // ---- layer 1 aggregate + FUSED layer-2 GEMM (writes hb2 directly)
    k_aggregate<true><<<AGG_BLOCKS, 256, 0, stream>>>(rowse, csr, (const uint2*)hb,
                                                      dis, b1, batch, nullptr, hb2, w2t,
                                                      nullptr, nullptr, nullptr, nullptr);
    // ---- layer 2 aggregate + fused mean-pool + tail-block head
    k_aggregate<false><<<AGG_BLOCKS, 256, 0, stream>>>(rowse, csr, (const uint2*)hb2,
                                                       dis, b2, batch, pooled,
                                                       nullptr, nullptr, done, Wl, bl, out);
}

// Round 13
// 249.750 us; speedup vs baseline: 5.1617x; 5.1617x over previous
//
#include <hip/hip_runtime.h>
#include <hip/hip_fp16.h>

#define N_NODES   100000
#define N_EDGES   1600000
#define IN_CH     128
#define HID       64
#define N_CLASSES 16
#define N_GRAPHS  64

#define BK_SH     9                          // bucket = dst >> 9 (512 nodes/bucket)
#define BK_NODES  512
#define NB        ((N_NODES + BK_NODES - 1) / BK_NODES)   // 196 buckets
#define BK_CAP    10240                      // fixed bucket capacity (mean 8163, +23 sigma)
#define CH_EDGES  4096
#define EPT       16                         // edges/thread in binscatter (256 thr)
#define NCH       ((N_EDGES + CH_EDGES - 1) / CH_EDGES)   // 391 chunks
#define AGG_NPW   2    // nodes per wave; 12500 blocks x 8 nodes = exact cover
#define AGG_BLOCKS (N_NODES / (4 * AGG_NPW))              // 12500

typedef __attribute__((ext_vector_type(8))) short bf16x8;
typedef __attribute__((ext_vector_type(4))) float f32x4;
typedef __attribute__((ext_vector_type(4))) unsigned u32x4;
typedef __attribute__((ext_vector_type(2))) unsigned u32x2;

__device__ __forceinline__ unsigned short f2bf(float f) {   // RNE f32->bf16
    unsigned u = __float_as_uint(f);
    u += 0x7fffu + ((u >> 16) & 1u);
    return (unsigned short)(u >> 16);
}
__device__ __forceinline__ f32x4 bf4v(uint2 v) {            // 4 bf16 -> f32x4
    u32x4 u;
    u.x = v.x << 16; u.y = v.x & 0xffff0000u;
    u.z = v.y << 16; u.w = v.y & 0xffff0000u;
    return __builtin_bit_cast(f32x4, u);
}
// csr entry: src (17 bits) | fp16(ew) sign-free (15 bits) << 17
__device__ __forceinline__ float dec_ew(unsigned v) {
    return __half2float(__ushort_as_half((unsigned short)(v >> 17)));
}

// ---- SRSRC buffer view: 32-bit voffset addressing for random gathers ----
#if __has_builtin(__builtin_amdgcn_make_buffer_rsrc) && \
    __has_builtin(__builtin_amdgcn_raw_buffer_load_b32) && \
    __has_builtin(__builtin_amdgcn_raw_buffer_load_b64)
struct BufView {
    __amdgpu_buffer_rsrc_t rsrc;
    __device__ __forceinline__ void init(const void* p) {
        rsrc = __builtin_amdgcn_make_buffer_rsrc((void*)p, (short)0,
                                                 (int)0xFFFFFFFF, 0x00020000);
    }
    __device__ __forceinline__ unsigned ld32(unsigned off) const {
        return __builtin_amdgcn_raw_buffer_load_b32(rsrc, (int)off, 0, 0);
    }
    __device__ __forceinline__ uint2 ld64(unsigned off) const {
        u32x2 r = __builtin_amdgcn_raw_buffer_load_b64(rsrc, (int)off, 0, 0);
        return make_uint2(r.x, r.y);
    }
};
#else
struct BufView {
    const char* base;
    __device__ __forceinline__ void init(const void* p) { base = (const char*)p; }
    __device__ __forceinline__ unsigned ld32(unsigned off) const {
        return *(const unsigned*)(base + off);
    }
    __device__ __forceinline__ uint2 ld64(unsigned off) const {
        return *(const uint2*)(base + off);
    }
};
#endif

// ---------------------------------------------------------------- bin scatter (staged)
// bcursor is zero-initialized (memset); absolute base = t*BK_CAP + running count.
__global__ void k_binscatter(const int* __restrict__ src, const int* __restrict__ dst,
                             const float* __restrict__ ew, int* __restrict__ bcursor,
                             int2* __restrict__ bedges) {
    __shared__ int  hist[NB];
    __shared__ int  offs[NB];
    __shared__ int  gbase[NB];
    __shared__ int  sc[256];
    __shared__ int2 stage[CH_EDGES];
    __shared__ int  dest[CH_EDGES];
    const int t = threadIdx.x;
    const int base = blockIdx.x * CH_EDGES;
    const int nloc = min(CH_EDGES, N_EDGES - base);

    for (int i = t; i < NB; i += 256) hist[i] = 0;
    __syncthreads();

    int myb[EPT], myr[EPT], myp[EPT]; float myw[EPT];
#pragma unroll
    for (int j = 0; j < EPT; ++j) {
        int i = base + j * 256 + t;
        if (i < N_EDGES) {
            int s = src[i], d = dst[i];
            int b = d >> BK_SH;
            myb[j] = b;
            myr[j] = atomicAdd(&hist[b], 1);
            myp[j] = s | ((d & (BK_NODES - 1)) << 17);
            myw[j] = ew[i];
        } else {
            myb[j] = -1;
        }
    }
    __syncthreads();

    int v = (t < NB) ? hist[t] : 0;
    sc[t] = v;
    __syncthreads();
    for (int off = 1; off < 256; off <<= 1) {
        int a = (t >= off) ? sc[t - off] : 0;
        __syncthreads();
        sc[t] += a;
        __syncthreads();
    }
    if (t < NB) {
        offs[t] = sc[t] - v;
        gbase[t] = t * BK_CAP + ((v > 0) ? atomicAdd(&bcursor[t], v) : 0);
    }
    __syncthreads();

#pragma unroll
    for (int j = 0; j < EPT; ++j) {
        if (myb[j] >= 0) {
            int p = offs[myb[j]] + myr[j];
            stage[p] = make_int2(myp[j], __float_as_int(myw[j]));
            dest[p] = gbase[myb[j]] + myr[j];
        }
    }
    __syncthreads();

    for (int i = t; i < nloc; i += 256)
        bedges[dest[i]] = stage[i];
}

// ---------------------------------------------------------------- build (fused)
// Grid NB+1: block NB performs the one-time bf16 weight transposes (w1t/w2t)
// consumed by gemm1 / fused agg1 epilogue; blocks 0..NB-1 build buckets.
__global__ __launch_bounds__(256) void k_build(const int* __restrict__ bcursor,
                                               const int2* __restrict__ bedges,
                                               int2* __restrict__ rowse,
                                               float* __restrict__ dis,
                                               unsigned* __restrict__ csr,
                                               const float* __restrict__ W1,
                                               const float* __restrict__ W2,
                                               unsigned short* __restrict__ w1t,
                                               unsigned short* __restrict__ w2t) {
    const int b = blockIdx.x;
    const int t = threadIdx.x;

    if (b == NB) {   // weight-transpose block
        for (int i = t; i < IN_CH * HID; i += 256) {   // w1t[n*128+k] = bf16(W1[k][n])
            int n = i >> 7, k = i & 127;
            w1t[i] = f2bf(W1[k * HID + n]);
        }
        for (int i = t; i < HID * HID; i += 256) {     // w2t[n*64+k] = bf16(W2[k][n])
            int n = i >> 6, k = i & 63;
            w2t[i] = f2bf(W2[k * HID + n]);
        }
        return;
    }

    __shared__ int2  eds[BK_CAP];         // 80 KB
    __shared__ int   cnt[BK_NODES];
    __shared__ float dsum[BK_NODES];
    __shared__ int   cur[BK_NODES];
    __shared__ int   sc[256];
    const int beg = b * BK_CAP;
    const int n = bcursor[b];             // per-bucket edge count

    for (int i = t; i < BK_NODES; i += 256) { cnt[i] = 0; dsum[i] = 0.0f; }
    __syncthreads();

    for (int i = t; i < n; i += 256) {
        int2 e = bedges[beg + i];
        eds[i] = e;
        int dl = ((unsigned)e.x) >> 17;
        atomicAdd(&cnt[dl], 1);
        atomicAdd(&dsum[dl], __int_as_float(e.y));
    }
    __syncthreads();

    int a0 = cnt[2 * t], a1 = cnt[2 * t + 1];
    int pair = a0 + a1;
    sc[t] = pair;
    __syncthreads();
    for (int off = 1; off < 256; off <<= 1) {
        int a = (t >= off) ? sc[t - off] : 0;
        __syncthreads();
        sc[t] += a;
        __syncthreads();
    }
    int excl = sc[t] - pair;
    cur[2 * t] = excl;
    cur[2 * t + 1] = excl + a0;
    {
        int n0 = b * BK_NODES + 2 * t;
        if (n0 < N_NODES) {
            rowse[n0] = make_int2(beg + excl, beg + excl + a0);
            dis[n0] = rsqrtf(1.0f + dsum[2 * t]);
        }
        int n1 = n0 + 1;
        if (n1 < N_NODES) {
            rowse[n1] = make_int2(beg + excl + a0, beg + excl + a0 + a1);
            dis[n1] = rsqrtf(1.0f + dsum[2 * t + 1]);
        }
    }
    __syncthreads();

    for (int i = t; i < n; i += 256) {
        int2 e = eds[i];
        int dl = ((unsigned)e.x) >> 17;
        int s = e.x & 0x1FFFF;
        unsigned short w16 = __half_as_ushort(__float2half(__int_as_float(e.y)));
        int pos = beg + atomicAdd(&cur[dl], 1);
        csr[pos] = (unsigned)s | ((unsigned)w16 << 17);
    }
}

// ---------------------------------------------------------------- GEMM via MFMA (layer 1)
// Epilogue scales by dis[row]: hb = bf16(dis * (x@W))  [norm factoring]
// Weights come pre-transposed+pre-converted (w1t): staging is a straight copy.
template <int K>
__global__ __launch_bounds__(256) void k_gemm(const float* __restrict__ x,
                                              const unsigned short* __restrict__ w1t,
                                              const float* __restrict__ dis,
                                              unsigned short* __restrict__ hb) {
    constexpr int AS = K + 8;            // padded stride in bf16 elems
    __shared__ unsigned short wt[64 * AS];    // wt[n][k] = W[k][n]
    __shared__ unsigned short a_s[64 * AS];   // a_s[row][k]
    const int t    = threadIdx.x;
    const int lane = t & 63;
    const int wave = t >> 6;
    const int m    = lane & 15;
    const int quad = lane >> 4;
    const int rowbase = blockIdx.x * 64;

    constexpr int CPR = K / 8;
    for (int c = t; c < 64 * CPR; c += 256) {
        int row = c / CPR, cc = c % CPR;
        int gr = rowbase + row;
        float4 v0, v1;
        if (gr < N_NODES) {
            v0 = *(const float4*)&x[(long)gr * K + cc * 8];
            v1 = *(const float4*)&x[(long)gr * K + cc * 8 + 4];
        } else {
            v0 = make_float4(0.f, 0.f, 0.f, 0.f); v1 = v0;
        }
        uint4 p;
        p.x = f2bf(v0.x) | ((unsigned)f2bf(v0.y) << 16);
        p.y = f2bf(v0.z) | ((unsigned)f2bf(v0.w) << 16);
        p.z = f2bf(v1.x) | ((unsigned)f2bf(v1.y) << 16);
        p.w = f2bf(v1.z) | ((unsigned)f2bf(v1.w) << 16);
        *(uint4*)&a_s[row * AS + cc * 8] = p;
    }
    // straight uint4 copy: coalesced global read, contiguous LDS write
    for (int idx = t; idx < 64 * CPR; idx += 256) {
        int n = idx / CPR, c = idx % CPR;
        *(uint4*)&wt[n * AS + c * 8] = *(const uint4*)&w1t[n * K + c * 8];
    }
    __syncthreads();

    bf16x8 afrag[K / 32];
#pragma unroll
    for (int ks = 0; ks < K / 32; ++ks)
        afrag[ks] = *(const bf16x8*)&a_s[(wave * 16 + m) * AS + ks * 32 + quad * 8];

    bf16x8 bfrag[4][K / 32];
#pragma unroll
    for (int nt = 0; nt < 4; ++nt)
#pragma unroll
        for (int ks = 0; ks < K / 32; ++ks)
            bfrag[nt][ks] = *(const bf16x8*)&wt[(nt * 16 + m) * AS + ks * 32 + quad * 8];

    f32x4 acc[4];
#pragma unroll
    for (int nt = 0; nt < 4; ++nt) acc[nt] = (f32x4){0.f, 0.f, 0.f, 0.f};

#pragma unroll
    for (int ks = 0; ks < K / 32; ++ks) {
#pragma unroll
        for (int nt = 0; nt < 4; ++nt)
            acc[nt] = __builtin_amdgcn_mfma_f32_16x16x32_bf16(afrag[ks], bfrag[nt][ks],
                                                              acc[nt], 0, 0, 0);
    }

#pragma unroll
    for (int i = 0; i < 4; ++i) {
        int gr = rowbase + wave * 16 + quad * 4 + i;
        if (gr < N_NODES) {
            float dsc = dis[gr];
#pragma unroll
            for (int nt = 0; nt < 4; ++nt)
                hb[(long)gr * HID + nt * 16 + m] = f2bf(dsc * acc[nt][i]);
        }
    }
}

// ---------------------------------------------------------------- aggregate (gather)
// Round-6 proven dual-chain gather. Each wave owns 2 consecutive nodes as two
// concurrent csr->gather->FMA streams (2x MLP), merged full-block loop +
// per-chain leftovers + interleaved clamped tails.
// OB=true : FUSED layer-2 GEMM epilogue (bit-identical to former k_gemm<64>).
// OB=false: fused global-mean-pool epilogue (LDS stage + run-length atomics).
// NOTE: no per-block device fences here — a __threadfence() in a wide grid
// cost 24x in round 12 (L2 writeback per block).

// process one full block for chain X: consume loaded csr regs, advance, prefetch
#define FULLBLK(pX, eX, f_, x0, x1, x2, x3, accX)                             \
    do {                                                                      \
        const unsigned e0_ = x0, e1_ = x1, e2_ = x2, e3_ = x3;                \
        pX += 16;                                                             \
        f_ = (pX + 16 <= eX);                                                 \
        if (f_) {                                                             \
            const unsigned v_ = (unsigned)((pX + g) << 2);                    \
            x0 = vc.ld32(v_);      x1 = vc.ld32(v_ + 16);                     \
            x2 = vc.ld32(v_ + 32); x3 = vc.ld32(v_ + 48);                     \
        }                                                                     \
        f32x4 v0_ = bf4v(vh.ld64(((e0_ & 0x1FFFF) << 7) | coff));             \
        f32x4 v1_ = bf4v(vh.ld64(((e1_ & 0x1FFFF) << 7) | coff));             \
        f32x4 v2_ = bf4v(vh.ld64(((e2_ & 0x1FFFF) << 7) | coff));             \
        f32x4 v3_ = bf4v(vh.ld64(((e3_ & 0x1FFFF) << 7) | coff));             \
        accX += v0_ * dec_ew(e0_);                                            \
        accX += v1_ * dec_ew(e1_);                                            \
        accX += v2_ * dec_ew(e2_);                                            \
        accX += v3_ * dec_ew(e3_);                                            \
    } while (0)

template <bool OB>
__global__ void k_aggregate(const int2* __restrict__ rowse,
                            const unsigned* __restrict__ csr,
                            const uint2* __restrict__ hb, const float* __restrict__ dis,
                            const float* __restrict__ b, const int* __restrict__ batch,
                            float* __restrict__ pooled,
                            unsigned short* __restrict__ hb2,
                            const unsigned short* __restrict__ w2t) {
    __shared__ float psh[4 * AGG_NPW][HID];        // 2 KB (pool path)
    __shared__ unsigned short wt2[64 * (HID + 8)]; // 9 KB W2 fragments (fuse path)
    __shared__ unsigned short prow[8][HID];        // 1 KB bf16 o-rows (fuse path)
    constexpr int AS2 = HID + 8;
    const int tid  = threadIdx.x;
    const int lane = tid & 63;
    const int g    = lane >> 4;          // edge group 0..3
    const int c4   = lane & 15;          // channel quad index
    const int wave = tid >> 6;
    const int node0 = (blockIdx.x * 4 + wave) * AGG_NPW;   // exact cover
    const int node1 = node0 + 1;
    const float4 bb = ((const float4*)b)[c4];
    const f32x4 bbv = {bb.x, bb.y, bb.z, bb.w};

    if constexpr (OB) {   // straight uint4 copy: coalesced read, contiguous write
        for (int idx = tid; idx < 64 * 8; idx += 256) {
            int n = idx >> 3, c = idx & 7;
            *(uint4*)&wt2[n * AS2 + c * 8] = *(const uint4*)&w2t[n * HID + c * 8];
        }
        __syncthreads();
    }

    BufView vc; vc.init(csr);            // 32-bit voffset addressing
    BufView vh; vh.init(hb);
    const unsigned coff = (unsigned)(c4 << 3);   // byte offset of my 8B slice in 128B row

    // both nodes' bounds (one 16B load, node0 even) + self-rows up front
    const int4 rr = *(const int4*)&rowse[node0];
    const uint2 hs0 = hb[node0 * 16 + c4];
    const uint2 hs1 = hb[node1 * 16 + c4];

    f32x4 acc0 = (g == 0) ? bf4v(hs0) : (f32x4){0.f, 0.f, 0.f, 0.f};
    f32x4 acc1 = (g == 0) ? bf4v(hs1) : (f32x4){0.f, 0.f, 0.f, 0.f};

    int p0 = rr.x; const int e0 = rr.y;
    int p1 = rr.z; const int e1 = rr.w;

    unsigned a0 = 0, a1 = 0, a2 = 0, a3 = 0;
    unsigned b0 = 0, b1 = 0, b2 = 0, b3 = 0;
    bool fA = (p0 + 16 <= e0);
    bool fB = (p1 + 16 <= e1);
    if (fA) {
        const unsigned v = (unsigned)((p0 + g) << 2);
        a0 = vc.ld32(v);      a1 = vc.ld32(v + 16);
        a2 = vc.ld32(v + 32); a3 = vc.ld32(v + 48);
    }
    if (fB) {
        const unsigned v = (unsigned)((p1 + g) << 2);
        b0 = vc.ld32(v);      b1 = vc.ld32(v + 16);
        b2 = vc.ld32(v + 32); b3 = vc.ld32(v + 48);
    }

    while (fA && fB) {          // both chains active: fully interleaved body
        FULLBLK(p0, e0, fA, a0, a1, a2, a3, acc0);
        FULLBLK(p1, e1, fB, b0, b1, b2, b3, acc1);
    }
    while (fA) FULLBLK(p0, e0, fA, a0, a1, a2, a3, acc0);
    while (fB) FULLBLK(p1, e1, fB, b0, b1, b2, b3, acc1);

    // interleaved clamped tails: issue both csr tail loads before any gather
    const bool tA = (p0 < e0);
    const bool tB = (p1 < e1);
    unsigned ta0 = 0, ta1 = 0, ta2 = 0, ta3 = 0;
    unsigned tb0 = 0, tb1 = 0, tb2 = 0, tb3 = 0;
    if (tA) {
        const int last = e0 - 1;
        ta0 = vc.ld32((unsigned)(min(p0 + g,      last) << 2));
        ta1 = vc.ld32((unsigned)(min(p0 + 4 + g,  last) << 2));
        ta2 = vc.ld32((unsigned)(min(p0 + 8 + g,  last) << 2));
        ta3 = vc.ld32((unsigned)(min(p0 + 12 + g, last) << 2));
    }
    if (tB) {
        const int last = e1 - 1;
        tb0 = vc.ld32((unsigned)(min(p1 + g,      last) << 2));
        tb1 = vc.ld32((unsigned)(min(p1 + 4 + g,  last) << 2));
        tb2 = vc.ld32((unsigned)(min(p1 + 8 + g,  last) << 2));
        tb3 = vc.ld32((unsigned)(min(p1 + 12 + g, last) << 2));
    }
    if (tA) {
        f32x4 v0 = bf4v(vh.ld64(((ta0 & 0x1FFFF) << 7) | coff));
        f32x4 v1 = bf4v(vh.ld64(((ta1 & 0x1FFFF) << 7) | coff));
        f32x4 v2 = bf4v(vh.ld64(((ta2 & 0x1FFFF) << 7) | coff));
        f32x4 v3 = bf4v(vh.ld64(((ta3 & 0x1FFFF) << 7) | coff));
        acc0 += v0 * ((p0 + g      < e0) ? dec_ew(ta0) : 0.f);
        acc0 += v1 * ((p0 + 4 + g  < e0) ? dec_ew(ta1) : 0.f);
        acc0 += v2 * ((p0 + 8 + g  < e0) ? dec_ew(ta2) : 0.f);
        acc0 += v3 * ((p0 + 12 + g < e0) ? dec_ew(ta3) : 0.f);
    }
    if (tB) {
        f32x4 v0 = bf4v(vh.ld64(((tb0 & 0x1FFFF) << 7) | coff));
        f32x4 v1 = bf4v(vh.ld64(((tb1 & 0x1FFFF) << 7) | coff));
        f32x4 v2 = bf4v(vh.ld64(((tb2 & 0x1FFFF) << 7) | coff));
        f32x4 v3 = bf4v(vh.ld64(((tb3 & 0x1FFFF) << 7) | coff));
        acc1 += v0 * ((p1 + g      < e1) ? dec_ew(tb0) : 0.f);
        acc1 += v1 * ((p1 + 4 + g  < e1) ? dec_ew(tb1) : 0.f);
        acc1 += v2 * ((p1 + 8 + g  < e1) ? dec_ew(tb2) : 0.f);
        acc1 += v3 * ((p1 + 12 + g < e1) ? dec_ew(tb3) : 0.f);
    }

    // cross-group reduce (4 groups of 16 lanes hold partial sums)
#pragma unroll
    for (int i = 0; i < 4; ++i) {
        float t0 = acc0[i];
        t0 += __shfl_xor(t0, 16); t0 += __shfl_xor(t0, 32);
        acc0[i] = t0;
        float t1 = acc1[i];
        t1 += __shfl_xor(t1, 16); t1 += __shfl_xor(t1, 32);
        acc1[i] = t1;
    }

    const float dd0 = dis[node0];
    const float dd1 = dis[node1];

    if (g == 0) {
        f32x4 o0 = acc0 * dd0 + bbv;
        f32x4 o1 = acc1 * dd1 + bbv;
        o0.x = fmaxf(o0.x, 0.f); o0.y = fmaxf(o0.y, 0.f);
        o0.z = fmaxf(o0.z, 0.f); o0.w = fmaxf(o0.w, 0.f);
        o1.x = fmaxf(o1.x, 0.f); o1.y = fmaxf(o1.y, 0.f);
        o1.z = fmaxf(o1.z, 0.f); o1.w = fmaxf(o1.w, 0.f);
        uint2 pk0, pk1;
        pk0.x = (unsigned)f2bf(o0.x) | ((unsigned)f2bf(o0.y) << 16);
        pk0.y = (unsigned)f2bf(o0.z) | ((unsigned)f2bf(o0.w) << 16);
        pk1.x = (unsigned)f2bf(o1.x) | ((unsigned)f2bf(o1.y) << 16);
        pk1.y = (unsigned)f2bf(o1.z) | ((unsigned)f2bf(o1.w) << 16);
        if constexpr (OB) {
            ((uint2*)prow)[(wave * 2) * 16 + c4]     = pk0;
            ((uint2*)prow)[(wave * 2 + 1) * 16 + c4] = pk1;
        } else {
            *(f32x4*)&psh[wave * AGG_NPW][c4 * 4] = o0;
            *(f32x4*)&psh[wave * AGG_NPW + 1][c4 * 4] = o1;
        }
    }

    if constexpr (OB) {    // ---- fused layer-2 mini-GEMM: hb2 = bf16(dis*(o@W2))
        __syncthreads();   // prow + wt2 visible to all
        const int mm = lane & 15;
        const int qq = lane >> 4;
        const int arow = wave * 2 + (mm < 2 ? mm : 0);   // rows>=2 are don't-care
        bf16x8 af0 = *(const bf16x8*)&prow[arow][qq * 8];
        bf16x8 af1 = *(const bf16x8*)&prow[arow][32 + qq * 8];
        f32x4 a2[4];
#pragma unroll
        for (int nt = 0; nt < 4; ++nt) a2[nt] = (f32x4){0.f, 0.f, 0.f, 0.f};
#pragma unroll
        for (int nt = 0; nt < 4; ++nt) {
            bf16x8 bf0 = *(const bf16x8*)&wt2[(nt * 16 + mm) * AS2 + qq * 8];
            a2[nt] = __builtin_amdgcn_mfma_f32_16x16x32_bf16(af0, bf0, a2[nt], 0, 0, 0);
        }
#pragma unroll
        for (int nt = 0; nt < 4; ++nt) {
            bf16x8 bf1 = *(const bf16x8*)&wt2[(nt * 16 + mm) * AS2 + 32 + qq * 8];
            a2[nt] = __builtin_amdgcn_mfma_f32_16x16x32_bf16(af1, bf1, a2[nt], 0, 0, 0);
        }
        if (qq == 0) {     // D: col=lane&15, row=(lane>>4)*4+i -> rows 0,1 here
#pragma unroll
            for (int nt = 0; nt < 4; ++nt) {
                hb2[(size_t)node0 * HID + nt * 16 + mm] = f2bf(dd0 * a2[nt][0]);
                hb2[(size_t)node1 * HID + nt * 16 + mm] = f2bf(dd1 * a2[nt][1]);
            }
        }
    }

    if constexpr (!OB) {   // fused mean-pool: run-length flush (batch sorted)
        __syncthreads();
        if (tid < HID) {
            const int nb0 = blockIdx.x * 4 * AGG_NPW;
            int curg = batch[nb0];
            float a = 0.f;
#pragma unroll
            for (int j = 0; j < 4 * AGG_NPW; ++j) {
                int bg = batch[nb0 + j];
                if (bg != curg) {
                    atomicAdd(&pooled[curg * HID + tid], a);
                    a = 0.f; curg = bg;
                }
                a += psh[j][tid];
            }
            atomicAdd(&pooled[curg * HID + tid], a);
        }
    }
}

// ---------------------------------------------------------------- head
// cnt[g] recovered by binary search over the sorted batch array.
__global__ __launch_bounds__(1024) void k_out(const float* __restrict__ pooled,
                      const int* __restrict__ batch,
                      const float* __restrict__ Wl, const float* __restrict__ bl,
                      float* __restrict__ out) {
    __shared__ int bnd[N_GRAPHS + 1];
    int tid = threadIdx.x;              // 1024 threads
    if (tid <= N_GRAPHS) {
        int target = tid;               // first idx with batch[idx] >= target
        int lo = 0, hi = N_NODES;
        while (lo < hi) {
            int mid = (lo + hi) >> 1;
            if (batch[mid] < target) lo = mid + 1; else hi = mid;
        }
        bnd[tid] = lo;
    }
    __syncthreads();
    int g = tid >> 4, k = tid & 15;
    float cntg = (float)(bnd[g + 1] - bnd[g]);
    float inv = 1.0f / fmaxf(cntg, 1.0f);
    float acc = 0.f;
#pragma unroll
    for (int h = 0; h < HID; ++h) acc += pooled[g * HID + h] * Wl[h * N_CLASSES + k];
    out[g * N_CLASSES + k] = acc * inv + bl[k];
}

extern "C" void kernel_launch(void* const* d_in, const int* in_sizes, int n_in,
                              void* d_out, int out_size, void* d_ws, size_t ws_size,
                              hipStream_t stream) {
    const float* x     = (const float*)d_in[0];
    const int*   ei    = (const int*)d_in[1];
    const float* ew    = (const float*)d_in[2];
    const int*   batch = (const int*)d_in[3];
    const float* W1    = (const float*)d_in[4];
    const float* b1    = (const float*)d_in[5];
    const float* W2    = (const float*)d_in[6];
    const float* b2    = (const float*)d_in[7];
    const float* Wl    = (const float*)d_in[8];
    const float* bl    = (const float*)d_in[9];

    const int* srcv = ei;            // edge_index[0]
    const int* dstv = ei + N_EDGES;  // edge_index[1]

    // workspace layout (all offsets 16B-aligned); zero-init region first
    char* wsb = (char*)d_ws;
    int*            bcursor= (int*)wsb;                wsb += 1024;             // counts (zeroed)
    float*          pooled = (float*)wsb;              wsb += N_GRAPHS * HID * 4; // 16 KB (zeroed)
    float*          dis    = (float*)wsb;              wsb += 100352 * 4;
    int2*           rowse  = (int2*)wsb;               wsb += 100352 * 8;   // {beg,end}/node
    unsigned*       csr    = (unsigned*)wsb;           wsb += (size_t)NB * BK_CAP * 4;
    unsigned short* hb     = (unsigned short*)wsb;     wsb += N_NODES * HID * 2;  // bf16 dis*h (layer1)
    char*           scratch= wsb;                      wsb += N_NODES * HID * 4;
    unsigned short* w1t    = (unsigned short*)wsb;     wsb += IN_CH * HID * 2;  // bf16 W1^T
    unsigned short* w2t    = (unsigned short*)wsb;     wsb += HID * HID * 2;    // bf16 W2^T
    float*          out    = (float*)d_out;
    int2*           bedges = (int2*)scratch;           // dead after k_build
    unsigned short* hb2    = (unsigned short*)scratch; // layer-2 gather rows (bf16),
                                                       // written by fused agg1 epilogue

    // ---- zero bcursor + pooled in one memset (replaces k_init)
    hipMemsetAsync(bcursor, 0, 1024 + N_GRAPHS * HID * 4, stream);

    // ---- CSR build (counting sort, fixed-capacity buckets, fused build + W transpose)
    k_binscatter<<<NCH, 256, 0, stream>>>(srcv, dstv, ew, bcursor, bedges);
    k_build<<<NB + 1, 256, 0, stream>>>(bcursor, bedges, rowse, dis, csr,
                                        W1, W2, w1t, w2t);

    // ---- layer 1 GEMM
    k_gemm<IN_CH><<<(N_NODES + 63) / 64, 256, 0, stream>>>(x, w1t, dis, hb);
    // ---- layer 1 aggregate + FUSED layer-2 GEMM (writes hb2 directly)
    k_aggregate<true><<<AGG_BLOCKS, 256, 0, stream>>>(rowse, csr, (const uint2*)hb,
                                                      dis, b1, batch, nullptr, hb2, w2t);
    // ---- layer 2 aggregate + fused mean-pool
    k_aggregate<false><<<AGG_BLOCKS, 256, 0, stream>>>(rowse, csr, (const uint2*)hb2,
                                                       dis, b2, batch, pooled,
                                                       nullptr, nullptr);

    // ---- head
    k_out<<<1, 1024, 0, stream>>>(pooled, batch, Wl, bl, out);
}